// Round 8
// baseline (116.168 us; speedup 1.0000x reference)
//
#include <hip/hip_runtime.h>
#include <math.h>

// ws layout (floats):
//   terms: [0, 6144)  256 pairs * 24 floats (pair-interleaved, 6 float4/pair):
//     f4[0]={-Lr0,-Lr1,Li0,Li1} f4[1]={t0r0,t0r1,t0i0,t0i1} f4[2]={t1r..}
//     f4[3]={t2r..} f4[4]={t3r..} f4[5]={Lr0^2,Lr1^2,t2s,0}
//   ZTp: [8192, +4*131072)  4 planes of 65536 float2: ZTp[q][t1*256 + l1]
constexpr int WS_TERMS = 0;
constexpr int WS_ZT    = 8192;

__device__ __forceinline__ float sin2pi(float x) { return __builtin_amdgcn_sinf(x); }
__device__ __forceinline__ float cos2pi(float x) { return __builtin_amdgcn_cosf(x); }

// ---------------------------------------------------------------------------
// Kernel 1: per-n setup.  Bc = Vc @ B (complex); pair-interleaved terms layout.
__global__ __launch_bounds__(256) void k_setup(
    const float* __restrict__ Lr, const float* __restrict__ Li,
    const float* __restrict__ pr, const float* __restrict__ pi,
    const float* __restrict__ qr, const float* __restrict__ qi,
    const float* __restrict__ Vr, const float* __restrict__ Vi,
    const float* __restrict__ Ct, const float* __restrict__ Bv,
    const float* __restrict__ log_step,
    float* __restrict__ terms)
{
    __shared__ float red[8];
    int n = blockIdx.x;
    int t = threadIdx.x;
    float b0 = Bv[t], b1 = Bv[t + 256];
    float sr = fmaf(Vr[n*512 + t], b0, Vr[n*512 + t + 256] * b1);
    float si = fmaf(Vi[n*512 + t], b0, Vi[n*512 + t + 256] * b1);
    #pragma unroll
    for (int off = 32; off > 0; off >>= 1) {
        sr += __shfl_down(sr, off, 64);
        si += __shfl_down(si, off, 64);
    }
    if ((t & 63) == 0) { red[(t >> 6)*2] = sr; red[(t >> 6)*2 + 1] = si; }
    __syncthreads();
    if (t == 0) {
        float b0r = red[0] + red[2] + red[4] + red[6];
        float b0i = red[1] + red[3] + red[5] + red[7];
        double step = exp((double)log_step[0]);
        float t2s = (float)(2.0 / step);
        float lr  = Lr[n];
        float a0r = Ct[2*n], a0i = -Ct[2*n+1];   // conj(Ct_c)
        float a1r = qr[n],   a1i = -qi[n];       // conj(q)
        float b1r = pr[n],   b1i = pi[n];        // p
        float* tm = terms + (n >> 1) * 24;
        int par = n & 1;
        tm[0  + par] = -lr;               tm[2  + par] = Li[n];
        tm[4  + par] = a0r*b0r - a0i*b0i; tm[6  + par] = a0r*b0i + a0i*b0r;
        tm[8  + par] = a0r*b1r - a0i*b1i; tm[10 + par] = a0r*b1i + a0i*b1r;
        tm[12 + par] = a1r*b0r - a1i*b0i; tm[14 + par] = a1r*b0i + a1i*b0r;
        tm[16 + par] = a1r*b1r - a1i*b1i; tm[18 + par] = a1r*b1i + a1i*b1r;
        tm[20 + par] = lr*lr;
        if (par == 0) { tm[22] = t2s; tm[23] = 0.f; }
    }
}

// ---------------------------------------------------------------------------
// Kernel 2: Cauchy + resolvent + partial DFT-A.  (r7 structure, proven.)
// 1024 blocks x 512 threads; block = (l1 = b>>2, quarter = b&3); 24 KB LDS
// -> 4 blocks/CU = 32 waves/CU.  Thread (u = tid&63, chunk = tid>>6 in [0,8)):
// l2 = quarter*64+u, n-pairs in [chunk*32, chunk*32+32).
// NEW (r8): pair-interleaved terms -> ds_read_b128 yields PACKED float2 operands;
// inner loop is elementwise float2 (SLP target: v_pk_fma_f32), ~22 slots / 2n.
// LDS overlay: terms[6144] | planes[4][64][9] + red[64][9]@2304 | xrow@0 + partA@128
__global__ __launch_bounds__(512, 8) void k_mainA(
    const float* __restrict__ terms,
    float* __restrict__ ZTf)
{
    __shared__ float buf[6144];   // 24 KB
    int tid = threadIdx.x;
    int b   = blockIdx.x;
    int l1      = b >> 2;
    int quarter = b & 3;

    // ---- stage terms -> LDS (1536 float4, 3 per thread, coalesced)
    {
        float4* dst = (float4*)buf;
        const float4* src = (const float4*)terms;
        #pragma unroll
        for (int i = 0; i < 3; ++i) dst[tid + 512*i] = src[tid + 512*i];
    }

    int u     = tid & 63;
    int chunk = tid >> 6;              // wave-uniform
    int l2    = quarter*64 + u;
    int l     = l1 + 256*l2;

    float tv2 = (float)l * (1.0f / 131072.0f);   // exact fp32 fraction
    float sn  = sin2pi(tv2), cn = cos2pi(tv2);
    float T   = sn / cn;                          // tan(pi*l/L)
    __syncthreads();                              // staging visible
    float t2s = buf[22];
    float g_i = t2s * T;
    // pole l = L/2: legit |T| <= ~2.1e4; anything bigger is the pole -> r=0, c~=1
    if (!(fabsf(T) <= 1.0e6f)) { g_i = 3e30f; T = 0.f; }

    float2 a0 = {0.f,0.f}, a1 = {0.f,0.f}, a2 = {0.f,0.f}, a3 = {0.f,0.f};
    float2 a4 = {0.f,0.f}, a5 = {0.f,0.f}, a6 = {0.f,0.f}, a7 = {0.f,0.f};

    const float4* t4 = (const float4*)buf + chunk * 32 * 6;
    #pragma unroll 4
    for (int p = 0; p < 32; ++p) {
        float4 q0 = t4[p*6 + 0];   // -Lr0,-Lr1, Li0, Li1   (broadcast ds_read_b128)
        float4 q1 = t4[p*6 + 1];   // t0r0,t0r1, t0i0,t0i1
        float4 q2 = t4[p*6 + 2];   // t1 pair
        float4 q3 = t4[p*6 + 3];   // t2 pair
        float4 q4 = t4[p*6 + 4];   // t3 pair
        float4 q5 = t4[p*6 + 5];   // Lr0^2, Lr1^2, t2s, 0
        float2 di, dd, iv, rr, ri;
        di.x = g_i - q0.z;                  di.y = g_i - q0.w;
        dd.x = fmaf(di.x, di.x, q5.x);      dd.y = fmaf(di.y, di.y, q5.y);
        iv.x = __builtin_amdgcn_rcpf(dd.x); iv.y = __builtin_amdgcn_rcpf(dd.y);
        rr.x = q0.x * iv.x;                 rr.y = q0.y * iv.y;
        ri.x = -di.x * iv.x;                ri.y = -di.y * iv.y;
        a0.x = fmaf(rr.x, q1.x, a0.x);  a0.y = fmaf(rr.y, q1.y, a0.y);
        a0.x = fmaf(-ri.x, q1.z, a0.x); a0.y = fmaf(-ri.y, q1.w, a0.y);
        a1.x = fmaf(rr.x, q1.z, a1.x);  a1.y = fmaf(rr.y, q1.w, a1.y);
        a1.x = fmaf( ri.x, q1.x, a1.x); a1.y = fmaf( ri.y, q1.y, a1.y);
        a2.x = fmaf(rr.x, q2.x, a2.x);  a2.y = fmaf(rr.y, q2.y, a2.y);
        a2.x = fmaf(-ri.x, q2.z, a2.x); a2.y = fmaf(-ri.y, q2.w, a2.y);
        a3.x = fmaf(rr.x, q2.z, a3.x);  a3.y = fmaf(rr.y, q2.w, a3.y);
        a3.x = fmaf( ri.x, q2.x, a3.x); a3.y = fmaf( ri.y, q2.y, a3.y);
        a4.x = fmaf(rr.x, q3.x, a4.x);  a4.y = fmaf(rr.y, q3.y, a4.y);
        a4.x = fmaf(-ri.x, q3.z, a4.x); a4.y = fmaf(-ri.y, q3.w, a4.y);
        a5.x = fmaf(rr.x, q3.z, a5.x);  a5.y = fmaf(rr.y, q3.w, a5.y);
        a5.x = fmaf( ri.x, q3.x, a5.x); a5.y = fmaf( ri.y, q3.y, a5.y);
        a6.x = fmaf(rr.x, q4.x, a6.x);  a6.y = fmaf(rr.y, q4.y, a6.y);
        a6.x = fmaf(-ri.x, q4.z, a6.x); a6.y = fmaf(-ri.y, q4.w, a6.y);
        a7.x = fmaf(rr.x, q4.z, a7.x);  a7.y = fmaf(rr.y, q4.w, a7.y);
        a7.x = fmaf( ri.x, q4.x, a7.x); a7.y = fmaf( ri.y, q4.y, a7.y);
    }
    float ac[8] = { a0.x + a0.y, a1.x + a1.y, a2.x + a2.y, a3.x + a3.y,
                    a4.x + a4.y, a5.x + a5.y, a6.x + a6.y, a7.x + a7.y };
    __syncthreads();   // terms reads done; LDS reusable

    // ---- fold 8 n-chunks -> 4 planes (chunks 4..7 write, 0..3 accumulate)
    if (chunk >= 4) {
        float* p = buf + (chunk - 4) * 576 + u * 9;
        #pragma unroll
        for (int c = 0; c < 8; ++c) p[c] = ac[c];
    }
    __syncthreads();
    if (chunk < 4) {
        float* p = buf + chunk * 576 + u * 9;
        #pragma unroll
        for (int c = 0; c < 8; ++c) p[c] += ac[c];
    }
    __syncthreads();

    // ---- stage-1: 512 slots (64 l2 x 8 comp), one per thread -> red @2304
    {
        int a = (tid >> 3) * 9 + (tid & 7);
        buf[2304 + a] = buf[a] + buf[576 + a] + buf[1152 + a] + buf[1728 + a];
    }
    __syncthreads();

    // ---- stage-2: atRoots for local l2 = tid (tid<64); own T (u=tid, chunk=0)
    if (tid < 64) {
        const float* rd = buf + 2304 + tid * 9;
        float s0r = rd[0], s0i = rd[1], s1r = rd[2], s1i = rd[3];
        float s2r = rd[4], s2i = rd[5], s3r = rd[6], s3i = rd[7];
        float e1r = 1.f + s3r, e1i = s3i;
        float eiv = 1.0f / fmaf(e1r, e1r, e1i * e1i);
        float m_r = s1r * s2r - s1i * s2i;
        float m_i = s1r * s2i + s1i * s2r;
        float q_r = (m_r * e1r + m_i * e1i) * eiv;
        float q_i = (m_i * e1r - m_r * e1i) * eiv;
        float u_r = s0r - q_r;
        float u_i = s0i - q_i;
        ((float2*)buf)[tid] = make_float2(u_r - T * u_i, u_i + T * u_r);  // xrow @0
    }
    __syncthreads();

    // ---- partial DFT-A over this quarter's 64 l2 (2-way split) + W_L twiddle
    {
        int t1 = tid & 255;
        int s  = tid >> 8;            // 0..1, wave-uniform
        int j0 = s * 32;
        int mm0 = ((quarter*64 + j0) * t1) & 255;
        float curR = cos2pi((float)mm0 * (1.0f/256.0f));
        float curI = sin2pi((float)mm0 * (1.0f/256.0f));
        float rotR = cos2pi((float)t1 * (1.0f/256.0f));
        float rotI = sin2pi((float)t1 * (1.0f/256.0f));
        const float2* xrow = (const float2*)buf;
        float yr = 0.f, yi = 0.f;
        #pragma unroll 8
        for (int j = j0; j < j0 + 32; ++j) {
            float2 x = xrow[j];   // broadcast
            yr = fmaf(x.x, curR, yr); yr = fmaf(-x.y, curI, yr);
            yi = fmaf(x.x, curI, yi); yi = fmaf( x.y, curR, yi);
            float nR = curR * rotR - curI * rotI;
            float nI = curR * rotI + curI * rotR;
            curR = nR; curI = nI;
        }
        ((float2*)(buf + 128))[tid] = make_float2(yr, yi);   // partA @128
    }
    __syncthreads();
    if (tid < 256) {
        const float2* pA = (const float2*)(buf + 128);
        float2 p0 = pA[tid], p1 = pA[tid + 256];
        float Yr = p0.x + p1.x;
        float Yi = p0.y + p1.y;
        int mm = (l1 * tid) & 65535;
        float tv = (float)mm * (1.0f / 65536.0f);
        float twR = cos2pi(tv), twI = sin2pi(tv);
        ((float2*)(ZTf + quarter * 131072))[tid * 256 + l1] =
            make_float2(Yr * twR - Yi * twI, Yr * twI + Yi * twR);
    }
}

// ---------------------------------------------------------------------------
// Kernel 3: DFT-B.  1024 blocks x 256 threads; block = (t1 = b>>2, qT = b&3)
// covers t2 in [qT*64, qT*64+64).  zrow = sum of 4 ZT planes.
__global__ __launch_bounds__(256) void k_fftB(
    const float* __restrict__ ZTf, float* __restrict__ out)
{
    __shared__ float buf2[768];    // zrow float2[256] @0, partB[256] @512
    int tid = threadIdx.x;
    int b   = blockIdx.x;
    int t1 = b >> 2;
    int qT = b & 3;
    {
        float2 z = make_float2(0.f, 0.f);
        #pragma unroll
        for (int q = 0; q < 4; ++q) {
            float2 v = ((const float2*)(ZTf + q * 131072))[t1 * 256 + tid];
            z.x += v.x; z.y += v.y;
        }
        ((float2*)buf2)[tid] = z;
    }
    int k2 = tid & 63;
    int s  = tid >> 6;            // 0..3, wave-uniform
    int t2 = qT * 64 + k2;
    int m0 = (s * t2) & 3;
    float curR = (m0 == 0) ? 1.f : (m0 == 2 ? -1.f : 0.f);
    float curI = (m0 == 1) ? 1.f : (m0 == 3 ? -1.f : 0.f);
    float rotR = cos2pi((float)t2 * (1.0f / 256.0f));
    float rotI = sin2pi((float)t2 * (1.0f / 256.0f));
    __syncthreads();
    const float2* zrow = (const float2*)buf2;
    float o = 0.f;
    #pragma unroll 8
    for (int j = s * 64; j < s * 64 + 64; ++j) {
        float2 z = zrow[j];   // broadcast
        o = fmaf(z.x, curR, o);
        o = fmaf(-z.y, curI, o);
        float nR = curR * rotR - curI * rotI;
        float nI = curR * rotI + curI * rotR;
        curR = nR; curI = nI;
    }
    buf2[512 + tid] = o;
    __syncthreads();
    if (tid < 64) {
        float sum = buf2[512+tid] + buf2[512+tid+64] + buf2[512+tid+128] + buf2[512+tid+192];
        out[t1 + 256 * (qT * 64 + tid)] = sum * (1.0f / 65536.0f);
    }
}

// ---------------------------------------------------------------------------
extern "C" void kernel_launch(void* const* d_in, const int* in_sizes, int n_in,
                              void* d_out, int out_size, void* d_ws, size_t ws_size,
                              hipStream_t stream)
{
    const float* Lambda_re = (const float*)d_in[0];
    const float* Lambda_im = (const float*)d_in[1];
    const float* p_re      = (const float*)d_in[2];
    const float* p_im      = (const float*)d_in[3];
    const float* q_re      = (const float*)d_in[4];
    const float* q_im      = (const float*)d_in[5];
    const float* Vc_re     = (const float*)d_in[6];
    const float* Vc_im     = (const float*)d_in[7];
    const float* Ct        = (const float*)d_in[8];
    const float* Bv        = (const float*)d_in[9];
    const float* log_step  = (const float*)d_in[10];

    float* wsf   = (float*)d_ws;
    float* terms = wsf + WS_TERMS;
    float* ZT    = wsf + WS_ZT;
    float* outp  = (float*)d_out;

    k_setup<<<512, 256, 0, stream>>>(Lambda_re, Lambda_im, p_re, p_im, q_re, q_im,
                                     Vc_re, Vc_im, Ct, Bv, log_step, terms);
    k_mainA<<<1024, 512, 0, stream>>>(terms, ZT);
    k_fftB<<<1024, 256, 0, stream>>>(ZT, outp);
}

// Round 9
// 106.275 us; speedup vs baseline: 1.0931x; 1.0931x over previous
//
#include <hip/hip_runtime.h>
#include <math.h>

// ws layout (floats):
//   terms: [0, 6144)    512*12: {-Lr, Li, t0r,t0i, t1r,t1i, t2r,t2i, t3r,t3i, Lr^2, t2s}
//   ZTp:   [8192, +4*131072)  4 planes of 65536 float2: ZTp[q][t1*256 + l1]
constexpr int WS_TERMS = 0;
constexpr int WS_ZT    = 8192;

__device__ __forceinline__ float sin2pi(float x) { return __builtin_amdgcn_sinf(x); }
__device__ __forceinline__ float cos2pi(float x) { return __builtin_amdgcn_cosf(x); }

// ---------------------------------------------------------------------------
// Kernel 1: per-n setup.  Bc = Vc @ B (complex); terms in r6 format.
__global__ __launch_bounds__(256) void k_setup(
    const float* __restrict__ Lr, const float* __restrict__ Li,
    const float* __restrict__ pr, const float* __restrict__ pi,
    const float* __restrict__ qr, const float* __restrict__ qi,
    const float* __restrict__ Vr, const float* __restrict__ Vi,
    const float* __restrict__ Ct, const float* __restrict__ Bv,
    const float* __restrict__ log_step,
    float* __restrict__ terms)
{
    __shared__ float red[8];
    int n = blockIdx.x;
    int t = threadIdx.x;
    float b0 = Bv[t], b1 = Bv[t + 256];
    float sr = fmaf(Vr[n*512 + t], b0, Vr[n*512 + t + 256] * b1);
    float si = fmaf(Vi[n*512 + t], b0, Vi[n*512 + t + 256] * b1);
    #pragma unroll
    for (int off = 32; off > 0; off >>= 1) {
        sr += __shfl_down(sr, off, 64);
        si += __shfl_down(si, off, 64);
    }
    if ((t & 63) == 0) { red[(t >> 6)*2] = sr; red[(t >> 6)*2 + 1] = si; }
    __syncthreads();
    if (t == 0) {
        float b0r = red[0] + red[2] + red[4] + red[6];
        float b0i = red[1] + red[3] + red[5] + red[7];
        double step = exp((double)log_step[0]);
        float t2s = (float)(2.0 / step);
        float lr  = Lr[n];
        float a0r = Ct[2*n], a0i = -Ct[2*n+1];   // conj(Ct_c)
        float a1r = qr[n],   a1i = -qi[n];       // conj(q)
        float b1r = pr[n],   b1i = pi[n];        // p
        float* tm = terms + n * 12;
        tm[0]  = -lr;                 tm[1]  = Li[n];
        tm[2]  = a0r*b0r - a0i*b0i;   tm[3]  = a0r*b0i + a0i*b0r;
        tm[4]  = a0r*b1r - a0i*b1i;   tm[5]  = a0r*b1i + a0i*b1r;
        tm[6]  = a1r*b0r - a1i*b0i;   tm[7]  = a1r*b0i + a1i*b0r;
        tm[8]  = a1r*b1r - a1i*b1i;   tm[9]  = a1r*b1i + a1i*b1r;
        tm[10] = lr*lr;               tm[11] = t2s;
    }
}

// ---------------------------------------------------------------------------
// Kernel 2: Cauchy + resolvent + partial DFT-A.
// 1024 blocks x 512 threads; block = (l1 = b>>2, quarter = b&3) covers
// l2 in [quarter*64, quarter*64+64).  Thread (u = tid&63, chunk = tid>>6 in [0,8)):
// one l2 = quarter*64+u, n in [chunk*64, chunk*64+64).  24 KB LDS -> 4 blocks/CU
// = 32 waves/CU (100% cap); 4 independent blocks overlap barrier phases.
// Analytic: g = i*t2s*tan(pi*l/L) (pure imaginary), c = 1 + i*tan(pi*l/L).
// LDS overlay: terms[6144] | planes[4][64][9]=2304 + red[64][9]@2304 | xrow@0 + partA@128
__global__ __launch_bounds__(512, 8) void k_mainA(
    const float* __restrict__ terms,
    float* __restrict__ ZTf)
{
    __shared__ float buf[6144];   // 24 KB
    int tid = threadIdx.x;
    int b   = blockIdx.x;
    int l1      = b >> 2;
    int quarter = b & 3;

    // ---- stage terms -> LDS (1536 float4, 3 per thread, coalesced)
    {
        float4* dst = (float4*)buf;
        const float4* src = (const float4*)terms;
        #pragma unroll
        for (int i = 0; i < 3; ++i) dst[tid + 512*i] = src[tid + 512*i];
    }

    int u     = tid & 63;
    int chunk = tid >> 6;              // wave-uniform
    int l2    = quarter*64 + u;
    int l     = l1 + 256*l2;

    float tv2 = (float)l * (1.0f / 131072.0f);   // exact fp32 fraction
    float sn  = sin2pi(tv2), cn = cos2pi(tv2);
    float T   = sn / cn;                          // tan(pi*l/L)
    __syncthreads();                              // staging visible
    float t2s = buf[11];
    float g_i = t2s * T;
    // pole l = L/2: legit |T| <= ~2.1e4; anything bigger is the pole -> r=0, c~=1
    if (!(fabsf(T) <= 1.0e6f)) { g_i = 3e30f; T = 0.f; }

    float ac[8];
    #pragma unroll
    for (int c = 0; c < 8; ++c) ac[c] = 0.f;

    const float4* t4 = (const float4*)buf + chunk * 64 * 3;
    #pragma unroll 4
    for (int n = 0; n < 64; ++n) {
        float4 Aq = t4[n*3 + 0];   // -Lr, Li, t0r, t0i  (broadcast ds_read_b128)
        float4 Bq = t4[n*3 + 1];   // t1r, t1i, t2r, t2i
        float4 Cq = t4[n*3 + 2];   // t3r, t3i, Lr^2, t2s
        float di = g_i - Aq.y;
        float dd = fmaf(di, di, Cq.z);           // di^2 + Lr^2; inf at pole -> r=0
        float iv = __builtin_amdgcn_rcpf(dd);
        float rr = Aq.x * iv;                    // (-Lr)/dd
        float ri = -di * iv;
        ac[0] = fmaf(rr, Aq.z, ac[0]); ac[0] = fmaf(-ri, Aq.w, ac[0]);
        ac[1] = fmaf(rr, Aq.w, ac[1]); ac[1] = fmaf( ri, Aq.z, ac[1]);
        ac[2] = fmaf(rr, Bq.x, ac[2]); ac[2] = fmaf(-ri, Bq.y, ac[2]);
        ac[3] = fmaf(rr, Bq.y, ac[3]); ac[3] = fmaf( ri, Bq.x, ac[3]);
        ac[4] = fmaf(rr, Bq.z, ac[4]); ac[4] = fmaf(-ri, Bq.w, ac[4]);
        ac[5] = fmaf(rr, Bq.w, ac[5]); ac[5] = fmaf( ri, Bq.z, ac[5]);
        ac[6] = fmaf(rr, Cq.x, ac[6]); ac[6] = fmaf(-ri, Cq.y, ac[6]);
        ac[7] = fmaf(rr, Cq.y, ac[7]); ac[7] = fmaf( ri, Cq.x, ac[7]);
    }
    __syncthreads();   // terms reads done; LDS reusable

    // ---- fold 8 n-chunks -> 4 planes (chunks 4..7 write, 0..3 accumulate)
    if (chunk >= 4) {
        float* p = buf + (chunk - 4) * 576 + u * 9;
        #pragma unroll
        for (int c = 0; c < 8; ++c) p[c] = ac[c];
    }
    __syncthreads();
    if (chunk < 4) {
        float* p = buf + chunk * 576 + u * 9;
        #pragma unroll
        for (int c = 0; c < 8; ++c) p[c] += ac[c];
    }
    __syncthreads();

    // ---- stage-1: 512 slots (64 l2 x 8 comp), one per thread -> red @2304
    {
        int a = (tid >> 3) * 9 + (tid & 7);
        buf[2304 + a] = buf[a] + buf[576 + a] + buf[1152 + a] + buf[1728 + a];
    }
    __syncthreads();

    // ---- stage-2: atRoots for local l2 = tid (tid<64); own T (u=tid, chunk=0)
    if (tid < 64) {
        const float* rd = buf + 2304 + tid * 9;
        float s0r = rd[0], s0i = rd[1], s1r = rd[2], s1i = rd[3];
        float s2r = rd[4], s2i = rd[5], s3r = rd[6], s3i = rd[7];
        float e1r = 1.f + s3r, e1i = s3i;
        float eiv = 1.0f / fmaf(e1r, e1r, e1i * e1i);
        float m_r = s1r * s2r - s1i * s2i;
        float m_i = s1r * s2i + s1i * s2r;
        float q_r = (m_r * e1r + m_i * e1i) * eiv;
        float q_i = (m_i * e1r - m_r * e1i) * eiv;
        float u_r = s0r - q_r;
        float u_i = s0i - q_i;
        ((float2*)buf)[tid] = make_float2(u_r - T * u_i, u_i + T * u_r);  // xrow @0
    }
    __syncthreads();

    // ---- partial DFT-A over this quarter's 64 l2 (2-way split) + W_L twiddle
    {
        int t1 = tid & 255;
        int s  = tid >> 8;            // 0..1, wave-uniform
        int j0 = s * 32;
        int mm0 = ((quarter*64 + j0) * t1) & 255;
        float curR = cos2pi((float)mm0 * (1.0f/256.0f));
        float curI = sin2pi((float)mm0 * (1.0f/256.0f));
        float rotR = cos2pi((float)t1 * (1.0f/256.0f));
        float rotI = sin2pi((float)t1 * (1.0f/256.0f));
        const float2* xrow = (const float2*)buf;
        float yr = 0.f, yi = 0.f;
        #pragma unroll 8
        for (int j = j0; j < j0 + 32; ++j) {
            float2 x = xrow[j];   // broadcast
            yr = fmaf(x.x, curR, yr); yr = fmaf(-x.y, curI, yr);
            yi = fmaf(x.x, curI, yi); yi = fmaf( x.y, curR, yi);
            float nR = curR * rotR - curI * rotI;
            float nI = curR * rotI + curI * rotR;
            curR = nR; curI = nI;
        }
        ((float2*)(buf + 128))[tid] = make_float2(yr, yi);   // partA @128
    }
    __syncthreads();
    if (tid < 256) {
        const float2* pA = (const float2*)(buf + 128);
        float2 p0 = pA[tid], p1 = pA[tid + 256];
        float Yr = p0.x + p1.x;
        float Yi = p0.y + p1.y;
        int mm = (l1 * tid) & 65535;
        float tv = (float)mm * (1.0f / 65536.0f);
        float twR = cos2pi(tv), twI = sin2pi(tv);
        ((float2*)(ZTf + quarter * 131072))[tid * 256 + l1] =
            make_float2(Yr * twR - Yi * twI, Yr * twI + Yi * twR);
    }
}

// ---------------------------------------------------------------------------
// Kernel 3: DFT-B.  1024 blocks x 256 threads; block = (t1 = b>>2, qT = b&3)
// covers t2 in [qT*64, qT*64+64).  zrow = sum of 4 ZT planes.
__global__ __launch_bounds__(256) void k_fftB(
    const float* __restrict__ ZTf, float* __restrict__ out)
{
    __shared__ float buf2[768];    // zrow float2[256] @0, partB[256] @512
    int tid = threadIdx.x;
    int b   = blockIdx.x;
    int t1 = b >> 2;
    int qT = b & 3;
    {
        float2 z = make_float2(0.f, 0.f);
        #pragma unroll
        for (int q = 0; q < 4; ++q) {
            float2 v = ((const float2*)(ZTf + q * 131072))[t1 * 256 + tid];
            z.x += v.x; z.y += v.y;
        }
        ((float2*)buf2)[tid] = z;
    }
    int k2 = tid & 63;
    int s  = tid >> 6;            // 0..3, wave-uniform
    int t2 = qT * 64 + k2;
    int m0 = (s * t2) & 3;
    float curR = (m0 == 0) ? 1.f : (m0 == 2 ? -1.f : 0.f);
    float curI = (m0 == 1) ? 1.f : (m0 == 3 ? -1.f : 0.f);
    float rotR = cos2pi((float)t2 * (1.0f / 256.0f));
    float rotI = sin2pi((float)t2 * (1.0f / 256.0f));
    __syncthreads();
    const float2* zrow = (const float2*)buf2;
    float o = 0.f;
    #pragma unroll 8
    for (int j = s * 64; j < s * 64 + 64; ++j) {
        float2 z = zrow[j];   // broadcast
        o = fmaf(z.x, curR, o);
        o = fmaf(-z.y, curI, o);
        float nR = curR * rotR - curI * rotI;
        float nI = curR * rotI + curI * rotR;
        curR = nR; curI = nI;
    }
    buf2[512 + tid] = o;
    __syncthreads();
    if (tid < 64) {
        float sum = buf2[512+tid] + buf2[512+tid+64] + buf2[512+tid+128] + buf2[512+tid+192];
        out[t1 + 256 * (qT * 64 + tid)] = sum * (1.0f / 65536.0f);
    }
}

// ---------------------------------------------------------------------------
extern "C" void kernel_launch(void* const* d_in, const int* in_sizes, int n_in,
                              void* d_out, int out_size, void* d_ws, size_t ws_size,
                              hipStream_t stream)
{
    const float* Lambda_re = (const float*)d_in[0];
    const float* Lambda_im = (const float*)d_in[1];
    const float* p_re      = (const float*)d_in[2];
    const float* p_im      = (const float*)d_in[3];
    const float* q_re      = (const float*)d_in[4];
    const float* q_im      = (const float*)d_in[5];
    const float* Vc_re     = (const float*)d_in[6];
    const float* Vc_im     = (const float*)d_in[7];
    const float* Ct        = (const float*)d_in[8];
    const float* Bv        = (const float*)d_in[9];
    const float* log_step  = (const float*)d_in[10];

    float* wsf   = (float*)d_ws;
    float* terms = wsf + WS_TERMS;
    float* ZT    = wsf + WS_ZT;
    float* outp  = (float*)d_out;

    k_setup<<<512, 256, 0, stream>>>(Lambda_re, Lambda_im, p_re, p_im, q_re, q_im,
                                     Vc_re, Vc_im, Ct, Bv, log_step, terms);
    k_mainA<<<1024, 512, 0, stream>>>(terms, ZT);
    k_fftB<<<1024, 256, 0, stream>>>(ZT, outp);
}